// Round 10
// baseline (169.660 us; speedup 1.0000x reference)
//
#include <hip/hip_runtime.h>
#include <hip/hip_bf16.h>

// out = (Q K^T * SCALE) @ V  ==  Q @ (SCALE * K^T V)   (softmax discarded in ref)
// B=32, T=2048, E=1024, H=64.  M = B*T = 65536.
// k_qkv (R10): PURE register pipeline.  No main-loop LDS, no barriers.
// x -> VGPR depth-2 (rA/rB); WT frags -> VGPR depth-1 dbuf (wA/wB) from L2.
// All loads for phase p+2 (x) / p+1 (B, via the dbuf) are issued at the END of
// phase p, before phase p+1's vmcnt asm (memory clobber pins them -> the
// compiler cannot sink the prefetch).  In-order retirement ledger:
//   at phase-p entry, outstanding = 16 (phase p-1's B12+X4) + 16 (p-2's, ours)
//   -> s_waitcnt vmcnt(16) retires our operands, keeps the newer 16.
//   A/B share folded K-permutation kappa: slot(ks,g,j) <-> k=32ks+16(j>>2)+4g+(j&3).

using bf16x8 = __attribute__((ext_vector_type(8))) short;
using f32x4  = __attribute__((ext_vector_type(4))) float;
using u32x4  = __attribute__((ext_vector_type(4))) unsigned int;
using u32x2  = __attribute__((ext_vector_type(2))) unsigned int;
using u16    = unsigned short;

__device__ __forceinline__ u16 f2bf(float f) {
    unsigned u = __builtin_bit_cast(unsigned, f);
    u += 0x7fffu + ((u >> 16) & 1u);          // RNE
    return (u16)(u >> 16);
}

// ---------------- k_wt: WT[n][c*64+kap] = W[c*64+w][n] (bf16, K-permuted) ----------------
__global__ __launch_bounds__(256) void k_wt(const float* __restrict__ Wq,
                                            const float* __restrict__ Wk,
                                            const float* __restrict__ Wv,
                                            u16* __restrict__ WT) {
    __shared__ float Wl[64][68];
    const int seg = blockIdx.x >> 4, chunk = blockIdx.x & 15;   // 48 blocks
    const float* W = (seg == 0) ? Wq : (seg == 1) ? Wk : Wv;
    const int e0 = chunk * 64;
    const int tid = threadIdx.x;
    const int lr = tid >> 4, lc = (tid & 15) * 4;
#pragma unroll
    for (int p = 0; p < 4; ++p)
        *(f32x4*)&Wl[lr + p * 16][lc] = *(const f32x4*)(W + (size_t)(e0 + lr + p * 16) * 64 + lc);
    __syncthreads();
    const int c = tid >> 2, eb = (tid & 3) * 16;
    u16* const dst = WT + (size_t)(seg * 64 + c) * 1024 + e0;
#pragma unroll
    for (int q = 0; q < 16; ++q) {
        const int w = eb + q;
        const int kap = ((w >> 5) << 5) | (((w >> 2) & 3) << 3) |
                        (((w >> 4) & 1) << 2) | (w & 3);
        dst[kap] = f2bf(Wl[w][c]);
    }
}

// ---------------- k_qkv: Q = x@Wq+bq (bf16 out) + fused partial K^T V ----------------
// 256 thr (4 waves, 2M x 2N), M-tile 64, N=192, BK=64, 16 chunks (rotated).
__global__ __launch_bounds__(256, 2) void k_qkv(const float* __restrict__ x,
                                                const u16* __restrict__ WT,
                                                const float* __restrict__ bq,
                                                const float* __restrict__ bk,
                                                const float* __restrict__ bv,
                                                u16* __restrict__ Qb,
                                                float* __restrict__ part) {
    __shared__ __align__(16) char lds[20480];     // epilogue Kt/Vt only
    const int tid  = threadIdx.x;
    const int wave = tid >> 6, lane = tid & 63;
    const int wm = wave >> 1, wcn = wave & 1;     // 2M x 2N wave grid
    const size_t row0 = (size_t)blockIdx.x * 64;
    const int off = blockIdx.x & 15;              // chunk rotation

    // x reg-direct: rows wm*32 + {0,16} + (lane&15); k-slot group g = lane>>4.
    const float* const xp0 = x + (row0 + wm * 32 + (lane & 15)) * 1024 + (lane >> 4) * 4;
    const float* const xp1 = xp0 + 16 * 1024;
    // WT reg-direct: row wcn*96 + n*16 + (lane&15); elems c*64 + ks*32 + g*8.
    const u16* const wp = WT + (size_t)(wcn * 96 + (lane & 15)) * 1024 + (lane >> 4) * 8;

    f32x4 acc[2][6];
#pragma unroll
    for (int m = 0; m < 2; ++m)
#pragma unroll
        for (int n = 0; n < 6; ++n)
#pragma unroll
            for (int r = 0; r < 4; ++r) acc[m][n][r] = 0.0f;

    f32x4 rA[8], rB[8];
    u32x4 wA[12], wB[12];                         // [n*2+ks]

#define BLOAD(W, P)                                                           \
    { const int c_ = (((P) + off) & 15) * 64;                                 \
      _Pragma("unroll") for (int t = 0; t < 12; ++t)                          \
          W[t] = *(const u32x4*)(wp + (size_t)(t >> 1) * 16384 + c_ + (t & 1) * 32); }

#define XLOAD(R, P)                                                           \
    { const int c_ = (((P) + off) & 15) * 64;                                 \
      _Pragma("unroll") for (int i = 0; i < 4; ++i) {                         \
          R[i]     = *(const f32x4*)(xp0 + c_ + i * 16);                      \
          R[4 + i] = *(const f32x4*)(xp1 + c_ + i * 16); } }

#define PHASE(P, W, R)                                                        \
    { if ((P) < 15) asm volatile("s_waitcnt vmcnt(16)" ::: "memory");         \
      else          asm volatile("s_waitcnt vmcnt(0)"  ::: "memory");         \
      __builtin_amdgcn_sched_barrier(0);                                      \
      _Pragma("unroll") for (int ks = 0; ks < 2; ++ks) {                      \
          u32x4 p0_, p1_;                                                     \
          { const f32x4 lo = R[2 * ks], hi = R[2 * ks + 1];                   \
            p0_[0] = (unsigned)f2bf(lo[0]) | ((unsigned)f2bf(lo[1]) << 16);   \
            p0_[1] = (unsigned)f2bf(lo[2]) | ((unsigned)f2bf(lo[3]) << 16);   \
            p0_[2] = (unsigned)f2bf(hi[0]) | ((unsigned)f2bf(hi[1]) << 16);   \
            p0_[3] = (unsigned)f2bf(hi[2]) | ((unsigned)f2bf(hi[3]) << 16); } \
          { const f32x4 lo = R[4 + 2 * ks], hi = R[4 + 2 * ks + 1];           \
            p1_[0] = (unsigned)f2bf(lo[0]) | ((unsigned)f2bf(lo[1]) << 16);   \
            p1_[1] = (unsigned)f2bf(lo[2]) | ((unsigned)f2bf(lo[3]) << 16);   \
            p1_[2] = (unsigned)f2bf(hi[0]) | ((unsigned)f2bf(hi[1]) << 16);   \
            p1_[3] = (unsigned)f2bf(hi[2]) | ((unsigned)f2bf(hi[3]) << 16); } \
          const bf16x8 a0 = __builtin_bit_cast(bf16x8, p0_);                  \
          const bf16x8 a1 = __builtin_bit_cast(bf16x8, p1_);                  \
          _Pragma("unroll") for (int n = 0; n < 6; ++n) {                     \
              const bf16x8 bf_ = __builtin_bit_cast(bf16x8, W[n * 2 + ks]);   \
              acc[0][n] = __builtin_amdgcn_mfma_f32_16x16x32_bf16(a0, bf_, acc[0][n], 0, 0, 0); \
              acc[1][n] = __builtin_amdgcn_mfma_f32_16x16x32_bf16(a1, bf_, acc[1][n], 0, 0, 0); \
          } }                                                                 \
      __builtin_amdgcn_sched_barrier(0);                                      \
      if ((P) + 2 < 16) { BLOAD(W, (P) + 2); XLOAD(R, (P) + 2); } }

    // ---- prologue: 2-deep prefetch, issue order = retirement order ----
    BLOAD(wA, 0); XLOAD(rA, 0);
    BLOAD(wB, 1); XLOAD(rB, 1);

    // ---- main loop: 16 phases, unroll-2 for static reg names ----
    for (int kk = 0; kk < 16; kk += 2) {
        PHASE(kk,     wA, rA);
        PHASE(kk + 1, wB, rB);
    }

    // ---- epilogue: Q -> global; K,V -> LDS transposed bf16 tiles (+bias) ----
    // D-layout: col = lane&15, row = (lane>>4)*4 + rr
    u16* const Kt = (u16*)lds;                    // [64][72]  (h_k major, 9216 B)
    u16* const Vt = (u16*)(lds + 10240);          // [64][72]  (h_v major)
#pragma unroll
    for (int n = 0; n < 6; ++n) {
        const int ncol = wcn * 96 + n * 16;
        const int seg = ncol >> 6;
        const int col = (ncol & 63) + (lane & 15);
        const float bias = ((seg == 0) ? bq : (seg == 1) ? bk : bv)[col];
#pragma unroll
        for (int m = 0; m < 2; ++m) {
            const int rloc = wm * 32 + m * 16 + ((lane >> 4) << 2);
            if (seg == 0) {
#pragma unroll
                for (int rr = 0; rr < 4; ++rr)
                    Qb[(row0 + rloc + rr) * 64 + col] = f2bf(acc[m][n][rr] + bias);
            } else {
                u16* const T = (seg == 1) ? Kt : Vt;
#pragma unroll
                for (int rr = 0; rr < 4; ++rr)
                    T[col * 72 + rloc + rr] = f2bf(acc[m][n][rr] + bias);
            }
        }
    }
    __syncthreads();

    // ---- fused K^T V partial: D[hv][hk] = sum_{64 rows} V[row][hv]*K[row][hk] ----
    float* const P = part + (size_t)blockIdx.x * 4096;
#pragma unroll
    for (int i = 0; i < 4; ++i) {
        const int f = wave * 4 + i;
        const int m0 = (f & 3) * 16;              // h_v
        const int n0 = (f >> 2) * 16;             // h_k
        f32x4 d;
        d[0] = d[1] = d[2] = d[3] = 0.0f;
#pragma unroll
        for (int ks = 0; ks < 2; ++ks) {
            const bf16x8 a = *(const bf16x8*)(Vt + (m0 + (lane & 15)) * 72 + ks * 32 + (lane >> 4) * 8);
            const bf16x8 b = *(const bf16x8*)(Kt + (n0 + (lane & 15)) * 72 + ks * 32 + (lane >> 4) * 8);
            d = __builtin_amdgcn_mfma_f32_16x16x32_bf16(a, b, d, 0, 0, 0);
        }
#pragma unroll
        for (int rr = 0; rr < 4; ++rr)
            P[(m0 + (lane >> 4) * 4 + rr) * 64 + n0 + (lane & 15)] = d[rr];
    }
#undef PHASE
#undef XLOAD
#undef BLOAD
}

// ---------------- k_red: KtVT[b][o] = SCALE * sum_c part[b*32+c][o], bf16 ----------------
__global__ __launch_bounds__(256) void k_red(const float* __restrict__ part,
                                             u16* __restrict__ KtVT) {
    const int b = blockIdx.x >> 2;
    const int o0 = (blockIdx.x & 3) * 1024 + threadIdx.x * 4;
    const float* const Pb = part + (size_t)b * 32 * 4096;
    f32x4 s;
    s[0] = s[1] = s[2] = s[3] = 0.0f;
#pragma unroll 8
    for (int c = 0; c < 32; ++c) s += *(const f32x4*)(Pb + c * 4096 + o0);
    s *= 0.125f;                                   // SCALE = 64^-0.5
    u32x2 pk;
    pk[0] = (unsigned)f2bf(s[0]) | ((unsigned)f2bf(s[1]) << 16);
    pk[1] = (unsigned)f2bf(s[2]) | ((unsigned)f2bf(s[3]) << 16);
    *(u32x2*)(KtVT + (size_t)b * 4096 + o0) = pk;
}

// ---------------- k_out: out = Q @ KtV (K=64), fp32 out ----------------
__global__ __launch_bounds__(256) void k_out(const u16* __restrict__ Qb,
                                             const u16* __restrict__ KtVT,
                                             float* __restrict__ out) {
    const int tid = threadIdx.x;
    const int wave = tid >> 6, lane = tid & 63;
    const size_t m0 = (size_t)blockIdx.x * 64 + wave * 16;
    const int b = blockIdx.x >> 5;            // 32 blocks per batch
    const u16* const Bp = KtVT + (size_t)b * 4096;

    bf16x8 bfrag[2][4];
#pragma unroll
    for (int ks = 0; ks < 2; ++ks)
#pragma unroll
        for (int nt = 0; nt < 4; ++nt)
            bfrag[ks][nt] = *(const bf16x8*)(Bp + (nt * 16 + (lane & 15)) * 64 + ks * 32 + (lane >> 4) * 8);

    f32x4 acc[4];
#pragma unroll
    for (int nt = 0; nt < 4; ++nt)
#pragma unroll
        for (int r = 0; r < 4; ++r) acc[nt][r] = 0.0f;

#pragma unroll
    for (int ks = 0; ks < 2; ++ks) {
        const bf16x8 a = *(const bf16x8*)(Qb + (m0 + (lane & 15)) * 64 + ks * 32 + (lane >> 4) * 8);
#pragma unroll
        for (int nt = 0; nt < 4; ++nt)
            acc[nt] = __builtin_amdgcn_mfma_f32_16x16x32_bf16(a, bfrag[ks][nt], acc[nt], 0, 0, 0);
    }
#pragma unroll
    for (int nt = 0; nt < 4; ++nt)
#pragma unroll
        for (int rr = 0; rr < 4; ++rr)
            out[(m0 + (lane >> 4) * 4 + rr) * 64 + nt * 16 + (lane & 15)] = acc[nt][rr];
}

extern "C" void kernel_launch(void* const* d_in, const int* in_sizes, int n_in,
                              void* d_out, int out_size, void* d_ws, size_t ws_size,
                              hipStream_t stream) {
    (void)in_sizes; (void)n_in; (void)out_size; (void)ws_size;
    const float* x  = (const float*)d_in[0];
    const float* Wq = (const float*)d_in[1];
    const float* bq = (const float*)d_in[2];
    const float* Wk = (const float*)d_in[3];
    const float* bk = (const float*)d_in[4];
    const float* Wv = (const float*)d_in[5];
    const float* bv = (const float*)d_in[6];
    float* out = (float*)d_out;

    char* ws = (char*)d_ws;                       // layout (~24.6 MB total):
    u16*  WT   = (u16*)(ws);                      // 0x0000000: 384 KB  WT bf16 [192][1024] (K-permuted)
    u16*  Qb   = (u16*)(ws + 0x60000);            // 0x0060000: 8 MB    Q bf16 [65536][64]
    float* part= (float*)(ws + 0x860000);         // 0x0860000: 16 MB   partials [1024][64][64] f32
    u16*  KtVT = (u16*)(ws + 0x1860000);          // 0x1860000: 256 KB  KtV^T bf16 [32][64][64]

    k_wt <<<48,   256, 0, stream>>>(Wq, Wk, Wv, WT);
    k_qkv<<<1024, 256, 0, stream>>>(x, WT, bq, bk, bv, Qb, part);
    k_red<<<128,  256, 0, stream>>>(part, KtVT);
    k_out<<<1024, 256, 0, stream>>>(Qb, KtVT, out);
}

// Round 11
// 101.607 us; speedup vs baseline: 1.6698x; 1.6698x over previous
//
#include <hip/hip_runtime.h>
#include <hip/hip_bf16.h>

// out = (Q K^T * SCALE) @ V  ==  Q @ (SCALE * K^T V)   (softmax discarded in ref)
// B=32, T=2048, E=1024, H=64.  M = B*T = 65536.
// k_qkv (R11 = proven P3 skeleton, re-parameterized): G2L16 dbuf staging for
// x and WT with pre-swizzled sources, counted vmcnt(5), 2 barriers/phase.
// K-chunk 32 -> 20 KB/buffer -> 40 KB LDS -> 4 blocks/CU (4 independent
// phase-clocks per CU); per-block chunk rotation decorrelates DRAM/L2.

using bf16x8 = __attribute__((ext_vector_type(8))) short;
using f32x4  = __attribute__((ext_vector_type(4))) float;
using u32x4  = __attribute__((ext_vector_type(4))) unsigned int;
using u32x2  = __attribute__((ext_vector_type(2))) unsigned int;
using u16    = unsigned short;

__device__ __forceinline__ u16 f2bf(float f) {
    unsigned u = __builtin_bit_cast(unsigned, f);
    u += 0x7fffu + ((u >> 16) & 1u);          // RNE
    return (u16)(u >> 16);
}

#define G2L16(g, l) __builtin_amdgcn_global_load_lds(                         \
    (const __attribute__((address_space(1))) void*)(g),                       \
    (__attribute__((address_space(3))) void*)(l), 16, 0, 0)

// ---------------- k_wt: WT[n][e] = W*[e][n] as bf16 (LDS transpose) ----------------
__global__ __launch_bounds__(256) void k_wt(const float* __restrict__ Wq,
                                            const float* __restrict__ Wk,
                                            const float* __restrict__ Wv,
                                            u16* __restrict__ WT) {
    __shared__ float Wl[64][68];
    const int seg = blockIdx.x >> 4, chunk = blockIdx.x & 15;   // 48 blocks
    const float* W = (seg == 0) ? Wq : (seg == 1) ? Wk : Wv;
    const int e0 = chunk * 64;
    const int tid = threadIdx.x;
    const int lr = tid >> 4, lc = (tid & 15) * 4;
#pragma unroll
    for (int p = 0; p < 4; ++p)
        *(f32x4*)&Wl[lr + p * 16][lc] = *(const f32x4*)(W + (size_t)(e0 + lr + p * 16) * 64 + lc);
    __syncthreads();
    const int c = tid >> 2, eb = (tid & 3) * 16;
    u32x4 o0, o1;
#pragma unroll
    for (int q = 0; q < 4; ++q)
        o0[q] = (unsigned)f2bf(Wl[eb + 2 * q][c]) | ((unsigned)f2bf(Wl[eb + 2 * q + 1][c]) << 16);
#pragma unroll
    for (int q = 0; q < 4; ++q)
        o1[q] = (unsigned)f2bf(Wl[eb + 8 + 2 * q][c]) | ((unsigned)f2bf(Wl[eb + 9 + 2 * q][c]) << 16);
    u16* dst = WT + (size_t)(seg * 64 + c) * 1024 + e0 + eb;
    *(u32x4*)dst = o0;
    *(u32x4*)(dst + 8) = o1;
}

// ---------------- k_qkv: Q = x@Wq+bq (bf16 out) + fused partial K^T V ----------------
// 256 thr (4 waves, 2M x 2N), M-tile 64, N=192, BK=32, 32 chunks (rotated).
// LDS per buf (20480 B): x f32 [64][32] @0 (8 KB, slot^(r&7)), WT bf16
// [192][32] @8192 (12 KB, slot^(n&3)).  dbuf 40 KB -> 4 blocks/CU.
// Staging: 5 G2L16/thread/chunk (x2 + WT3), sources pre-swizzled, dests linear.
// Ledger: at phase p, outstanding = stage(p).5 + stage(p+1).5 -> vmcnt(5);
// p==31 -> vmcnt(0).  Two barriers/phase (dbuf WAR).
__global__ __launch_bounds__(256, 4) void k_qkv(const float* __restrict__ x,
                                                const u16* __restrict__ WT,
                                                const float* __restrict__ bq,
                                                const float* __restrict__ bk,
                                                const float* __restrict__ bv,
                                                u16* __restrict__ Qb,
                                                float* __restrict__ part) {
    __shared__ __align__(16) char lds[40960];
    const int tid  = threadIdx.x;
    const int wave = tid >> 6, lane = tid & 63;
    const int wm = wave >> 1, wcn = wave & 1;     // 2M x 2N wave grid
    const int g = lane >> 4;
    const size_t row0 = (size_t)blockIdx.x * 64;
    const int off = blockIdx.x & 31;              // chunk rotation

    // x staging: instr i covers rows [32i, 32i+32); this lane -> row r, slot l&7.
    size_t xsrc[2]; int xdst[2];
#pragma unroll
    for (int i = 0; i < 2; ++i) {
        const int r  = 32 * i + 8 * wave + (lane >> 3);
        const int sl = (lane & 7) ^ (r & 7);      // pre-swizzled source slot
        xsrc[i] = (row0 + r) * 1024 + sl * 4;     // f32 elems; +c*32 per chunk
        xdst[i] = i * 4096 + wave * 1024;         // wave-uniform; HW adds lane*16
    }
    // WT staging: instr j covers rows [64j, 64j+64); this lane -> row n, slot l&3.
    size_t wsrc[3]; int wdst[3];
#pragma unroll
    for (int j = 0; j < 3; ++j) {
        const int n  = 64 * j + 16 * wave + (lane >> 2);
        const int sl = (lane & 3) ^ (n & 3);
        wsrc[j] = (size_t)n * 1024 + sl * 8;      // bf16 elems; +c*32 per chunk
        wdst[j] = 8192 + j * 4096 + wave * 1024;
    }

    f32x4 acc[2][6];
#pragma unroll
    for (int m = 0; m < 2; ++m)
#pragma unroll
        for (int n = 0; n < 6; ++n)
#pragma unroll
            for (int r = 0; r < 4; ++r) acc[m][n][r] = 0.0f;

#define STAGE(P)                                                              \
    { const int c_ = (((P) + off) & 31) * 32;                                 \
      char* const b_ = lds + (((P) & 1) ? 20480 : 0);                         \
      G2L16(x + xsrc[0] + c_, b_ + xdst[0]);                                  \
      G2L16(x + xsrc[1] + c_, b_ + xdst[1]);                                  \
      G2L16(WT + wsrc[0] + c_, b_ + wdst[0]);                                 \
      G2L16(WT + wsrc[1] + c_, b_ + wdst[1]);                                 \
      G2L16(WT + wsrc[2] + c_, b_ + wdst[2]); }

    // prologue: stage chunk 0 into buf 0
    STAGE(0);

#pragma unroll 2
    for (int p = 0; p < 32; ++p) {
        if (p < 31) STAGE(p + 1);
        if (p < 31) asm volatile("s_waitcnt vmcnt(5)" ::: "memory");
        else        asm volatile("s_waitcnt vmcnt(0)" ::: "memory");
        __builtin_amdgcn_s_barrier();
        __builtin_amdgcn_sched_barrier(0);

        const char* const xb = lds + (p & 1) * 20480;
        const char* const wb = xb + 8192;
        bf16x8 af[2];
#pragma unroll
        for (int m = 0; m < 2; ++m) {
            const int r = wm * 32 + m * 16 + (lane & 15);
            const int base = r * 128, swz = (r & 7) << 4;
            const f32x4 lo = *(const f32x4*)(xb + (base + ((g * 32)      ^ swz)));
            const f32x4 hi = *(const f32x4*)(xb + (base + ((g * 32 + 16) ^ swz)));
            u32x4 pk;
            pk[0] = (unsigned)f2bf(lo[0]) | ((unsigned)f2bf(lo[1]) << 16);
            pk[1] = (unsigned)f2bf(lo[2]) | ((unsigned)f2bf(lo[3]) << 16);
            pk[2] = (unsigned)f2bf(hi[0]) | ((unsigned)f2bf(hi[1]) << 16);
            pk[3] = (unsigned)f2bf(hi[2]) | ((unsigned)f2bf(hi[3]) << 16);
            af[m] = __builtin_bit_cast(bf16x8, pk);
        }
#pragma unroll
        for (int n = 0; n < 6; ++n) {
            const int nn = wcn * 96 + n * 16 + (lane & 15);
            const bf16x8 bfr = *(const bf16x8*)(wb + (nn * 64 + ((g * 16) ^ ((nn & 3) << 4))));
            acc[0][n] = __builtin_amdgcn_mfma_f32_16x16x32_bf16(af[0], bfr, acc[0][n], 0, 0, 0);
            acc[1][n] = __builtin_amdgcn_mfma_f32_16x16x32_bf16(af[1], bfr, acc[1][n], 0, 0, 0);
        }
        __builtin_amdgcn_sched_barrier(0);
        __builtin_amdgcn_s_barrier();             // dbuf WAR guard
    }
#undef STAGE

    // ---- epilogue: Q -> global; K,V -> LDS transposed bf16 tiles (+bias) ----
    // D-layout: col = lane&15, row = (lane>>4)*4 + rr
    u16* const Kt = (u16*)lds;                    // [64][72]  (h_k major, 9216 B)
    u16* const Vt = (u16*)(lds + 10240);          // [64][72]  (h_v major)
#pragma unroll
    for (int n = 0; n < 6; ++n) {
        const int ncol = wcn * 96 + n * 16;
        const int seg = ncol >> 6;
        const int col = (ncol & 63) + (lane & 15);
        const float bias = ((seg == 0) ? bq : (seg == 1) ? bk : bv)[col];
#pragma unroll
        for (int m = 0; m < 2; ++m) {
            const int rloc = wm * 32 + m * 16 + (g << 2);
            if (seg == 0) {
#pragma unroll
                for (int rr = 0; rr < 4; ++rr)
                    Qb[(row0 + rloc + rr) * 64 + col] = f2bf(acc[m][n][rr] + bias);
            } else {
                u16* const T = (seg == 1) ? Kt : Vt;
#pragma unroll
                for (int rr = 0; rr < 4; ++rr)
                    T[col * 72 + rloc + rr] = f2bf(acc[m][n][rr] + bias);
            }
        }
    }
    __syncthreads();

    // ---- fused K^T V partial: D[hv][hk] = sum_{64 rows} V[row][hv]*K[row][hk] ----
    float* const P = part + (size_t)blockIdx.x * 4096;
#pragma unroll
    for (int i = 0; i < 4; ++i) {
        const int f = wave * 4 + i;
        const int m0 = (f & 3) * 16;              // h_v
        const int n0 = (f >> 2) * 16;             // h_k
        f32x4 d;
        d[0] = d[1] = d[2] = d[3] = 0.0f;
#pragma unroll
        for (int ks = 0; ks < 2; ++ks) {
            const bf16x8 a = *(const bf16x8*)(Vt + (m0 + (lane & 15)) * 72 + ks * 32 + g * 8);
            const bf16x8 b = *(const bf16x8*)(Kt + (n0 + (lane & 15)) * 72 + ks * 32 + g * 8);
            d = __builtin_amdgcn_mfma_f32_16x16x32_bf16(a, b, d, 0, 0, 0);
        }
#pragma unroll
        for (int rr = 0; rr < 4; ++rr)
            P[(m0 + g * 4 + rr) * 64 + n0 + (lane & 15)] = d[rr];
    }
}

// ---------------- k_red: KtVT[b][o] = SCALE * sum_c part[b*32+c][o], bf16 ----------------
__global__ __launch_bounds__(256) void k_red(const float* __restrict__ part,
                                             u16* __restrict__ KtVT) {
    const int b = blockIdx.x >> 2;
    const int o0 = (blockIdx.x & 3) * 1024 + threadIdx.x * 4;
    const float* const Pb = part + (size_t)b * 32 * 4096;
    f32x4 s;
    s[0] = s[1] = s[2] = s[3] = 0.0f;
#pragma unroll 8
    for (int c = 0; c < 32; ++c) s += *(const f32x4*)(Pb + c * 4096 + o0);
    s *= 0.125f;                                   // SCALE = 64^-0.5
    u32x2 pk;
    pk[0] = (unsigned)f2bf(s[0]) | ((unsigned)f2bf(s[1]) << 16);
    pk[1] = (unsigned)f2bf(s[2]) | ((unsigned)f2bf(s[3]) << 16);
    *(u32x2*)(KtVT + (size_t)b * 4096 + o0) = pk;
}

// ---------------- k_out: out = Q @ KtV (K=64), fp32 out ----------------
__global__ __launch_bounds__(256) void k_out(const u16* __restrict__ Qb,
                                             const u16* __restrict__ KtVT,
                                             float* __restrict__ out) {
    const int tid = threadIdx.x;
    const int wave = tid >> 6, lane = tid & 63;
    const size_t m0 = (size_t)blockIdx.x * 64 + wave * 16;
    const int b = blockIdx.x >> 5;            // 32 blocks per batch
    const u16* const Bp = KtVT + (size_t)b * 4096;

    bf16x8 bfrag[2][4];
#pragma unroll
    for (int ks = 0; ks < 2; ++ks)
#pragma unroll
        for (int nt = 0; nt < 4; ++nt)
            bfrag[ks][nt] = *(const bf16x8*)(Bp + (nt * 16 + (lane & 15)) * 64 + ks * 32 + (lane >> 4) * 8);

    f32x4 acc[4];
#pragma unroll
    for (int nt = 0; nt < 4; ++nt)
#pragma unroll
        for (int r = 0; r < 4; ++r) acc[nt][r] = 0.0f;

#pragma unroll
    for (int ks = 0; ks < 2; ++ks) {
        const bf16x8 a = *(const bf16x8*)(Qb + (m0 + (lane & 15)) * 64 + ks * 32 + (lane >> 4) * 8);
#pragma unroll
        for (int nt = 0; nt < 4; ++nt)
            acc[nt] = __builtin_amdgcn_mfma_f32_16x16x32_bf16(a, bfrag[ks][nt], acc[nt], 0, 0, 0);
    }
#pragma unroll
    for (int nt = 0; nt < 4; ++nt)
#pragma unroll
        for (int rr = 0; rr < 4; ++rr)
            out[(m0 + (lane >> 4) * 4 + rr) * 64 + nt * 16 + (lane & 15)] = acc[nt][rr];
}

extern "C" void kernel_launch(void* const* d_in, const int* in_sizes, int n_in,
                              void* d_out, int out_size, void* d_ws, size_t ws_size,
                              hipStream_t stream) {
    (void)in_sizes; (void)n_in; (void)out_size; (void)ws_size;
    const float* x  = (const float*)d_in[0];
    const float* Wq = (const float*)d_in[1];
    const float* bq = (const float*)d_in[2];
    const float* Wk = (const float*)d_in[3];
    const float* bk = (const float*)d_in[4];
    const float* Wv = (const float*)d_in[5];
    const float* bv = (const float*)d_in[6];
    float* out = (float*)d_out;

    char* ws = (char*)d_ws;                       // layout (~24.6 MB total):
    u16*  WT   = (u16*)(ws);                      // 0x0000000: 384 KB  WT bf16 [192][1024]
    u16*  Qb   = (u16*)(ws + 0x60000);            // 0x0060000: 8 MB    Q bf16 [65536][64]
    float* part= (float*)(ws + 0x860000);         // 0x0860000: 16 MB   partials [1024][64][64] f32
    u16*  KtVT = (u16*)(ws + 0x1860000);          // 0x1860000: 256 KB  KtV^T bf16 [32][64][64]

    k_wt <<<48,   256, 0, stream>>>(Wq, Wk, Wv, WT);
    k_qkv<<<1024, 256, 0, stream>>>(x, WT, bq, bk, bv, Qb, part);
    k_red<<<128,  256, 0, stream>>>(part, KtVT);
    k_out<<<1024, 256, 0, stream>>>(Qb, KtVT, out);
}